// Round 5
// baseline (407.967 us; speedup 1.0000x reference)
//
#include <hip/hip_runtime.h>

// LJ pair energy, fused edge->molecule scatter. One lane = one edge,
// grid-stride unrolled x8 for memory-level parallelism.
// R_EQ=1, WELL_DEPTH=1, CUTOFF=2.5, HEAL=0.5.
#define RCUT2  6.25f    // CUTOFF^2
#define RIN2   4.0f     // (CUTOFF-HEAL)^2
#define BT     512
#define UNROLL 8

struct __attribute__((aligned(4))) F3 { float x, y, z; };   // 12 B, no padding

// zero out[] and init uniform-flag
__global__ __launch_bounds__(256) void init_k(float* __restrict__ out, int n_mol,
                                              int* __restrict__ flag, int flag_init) {
    int i = blockIdx.x * 256 + threadIdx.x;
    if (i < n_mol) out[i] = 0.0f;
    if (i == 0) *flag = flag_init;
}

// Build molecule start offsets from sorted idx_m; verify idx_m matches the
// uniform formula (a*n_mol)/n_atoms (u64 div = ground truth).
__global__ __launch_bounds__(256) void build_bounds(
    const int* __restrict__ idx_m, int* __restrict__ start,
    int* __restrict__ flag, int n_atoms, int n_mol) {
    int a = blockIdx.x * 256 + threadIdx.x;
    if (a >= n_atoms) return;
    int m  = idx_m[a];
    int pm = (a == 0) ? -1 : idx_m[a - 1];
    for (int mm = pm + 1; mm <= m; ++mm) start[mm] = a;
    if (a == n_atoms - 1)
        for (int mm = m + 1; mm <= n_mol; ++mm) start[mm] = n_atoms;
    int mf = (int)(((unsigned long long)(unsigned)a * (unsigned)n_mol) / (unsigned)n_atoms);
    if (m != mf) atomicAnd(flag, 0);
}

__device__ __forceinline__ void lj_accum(
    float* __restrict__ bins, F3 v, int a, int n_mol,
    unsigned long long M, int sh, bool uni, const int* __restrict__ bounds_g) {
    float r2 = fmaf(v.x, v.x, fmaf(v.y, v.y, v.z * v.z));
    if (r2 > RCUT2) return;             // switch == 0 exactly

    float inv2 = __builtin_amdgcn_rcpf(r2);     // v_rcp_f32 (tol >> 1 ulp)
    float p6   = inv2 * inv2 * inv2;
    float y    = fmaf(p6, p6, -p6);     // p12 - p6

    float r  = __builtin_amdgcn_sqrtf(r2);
    float t  = fmaf(2.0f, r, -4.0f);    // (r - 2)/0.5
    float sw = fmaf(t * t, fmaf(2.0f, t, -3.0f), 1.0f);
    y *= (r2 > RIN2) ? sw : 1.0f;

    unsigned q = (unsigned)a * (unsigned)n_mol;
    int m = (int)(((unsigned long long)q * M) >> sh);
    if (!uni) {                         // general sorted-idx_m fallback
        if (m > n_mol - 1) m = n_mol - 1;
        if (m < 0) m = 0;
        while (m > 0 && a < bounds_g[m]) --m;
        while (m < n_mol - 1 && a >= bounds_g[m + 1]) ++m;
    }
    atomicAdd(&bins[m], y);             // ds_add_f32
}

__global__ __launch_bounds__(BT) void lj_direct(
    const F3*  __restrict__ vec3,
    const int* __restrict__ idx_i,
    const int* __restrict__ bounds_g,   // n_mol+1 (global; fallback only)
    const int* __restrict__ flag,
    float*     __restrict__ out,
    int n_edges, int n_mol,
    unsigned long long M, int sh)
{
    extern __shared__ float bins[];     // n_mol fp32
    for (int i = threadIdx.x; i < n_mol; i += BT) bins[i] = 0.0f;
    const bool uni = (*flag != 0);      // wave-uniform
    __syncthreads();

    const int S = gridDim.x * BT;
    int e = blockIdx.x * BT + threadIdx.x;

    // unrolled-by-8: 16 independent loads in flight per wave before any use
    for (; e + (UNROLL - 1) * S < n_edges; e += UNROLL * S) {
        F3  v[UNROLL];
        int a[UNROLL];
        #pragma unroll
        for (int j = 0; j < UNROLL; ++j) {
            v[j] = vec3[e + j * S];     // global_load_dwordx3, coalesced
            a[j] = idx_i[e + j * S];    // global_load_dword,   coalesced
        }
        #pragma unroll
        for (int j = 0; j < UNROLL; ++j)
            lj_accum(bins, v[j], a[j], n_mol, M, sh, uni, bounds_g);
    }
    // remainder
    for (; e < n_edges; e += S)
        lj_accum(bins, vec3[e], idx_i[e], n_mol, M, sh, uni, bounds_g);

    __syncthreads();
    // rotated flush spreads global-atomic contention across bins
    unsigned off = (blockIdx.x * 131u) % (unsigned)n_mol;
    for (int i = threadIdx.x; i < n_mol; i += BT) {
        int j = i + (int)off; if (j >= n_mol) j -= n_mol;
        float bv = bins[j];
        if (bv != 0.0f) atomicAdd(&out[j], 0.5f * bv);   // WELL_DEPTH * 0.5
    }
}

extern "C" void kernel_launch(void* const* d_in, const int* in_sizes, int n_in,
                              void* d_out, int out_size, void* d_ws, size_t ws_size,
                              hipStream_t stream) {
    const float* vec   = (const float*)d_in[0];
    const int*   idx_i = (const int*)d_in[2];
    const int*   idx_m = (const int*)d_in[3];
    float*       out   = (float*)d_out;

    const int n_edges = in_sizes[2];
    const int n_atoms = in_sizes[3];
    const int n_mol   = out_size;

    int* start = (int*)d_ws;                  // n_mol+1 ints
    int* flag  = (int*)d_ws + (n_mol + 2);    // 1 int

    // magic divisor for q/n_atoms, q = a*n_mol < 2^31:
    // M = 2^sh/d + 1; exact for all q < 2^31 iff M*d - 2^sh <= 2^(sh-31)
    unsigned d = (unsigned)n_atoms;
    unsigned long long M = 1; int sh = 32;
    bool ok = ((unsigned long long)(unsigned)n_mol * d) <= 0x7fffffffull;
    if (ok) {
        bool found = false;
        for (sh = 32; sh <= 62; ++sh) {
            unsigned long long tk = 1ull << sh;
            M = tk / d + 1;
            unsigned long long err = M * d - tk;
            if (err <= (1ull << (sh - 31))) { found = true; break; }
        }
        ok = found;
    }
    if (!ok) { M = 0; sh = 0; }               // forces fallback path

    init_k<<<(n_mol + 255) / 256, 256, 0, stream>>>(out, n_mol, flag, ok ? 1 : 0);
    build_bounds<<<(n_atoms + 255) / 256, 256, 0, stream>>>(idx_m, start, flag, n_atoms, n_mol);

    const int    nb  = 1024;                  // 4 blocks/CU x 512 = 32 waves/CU
    const size_t lds = (size_t)n_mol * sizeof(float);
    lj_direct<<<nb, BT, lds, stream>>>(
        (const F3*)vec, idx_i, start, flag, out, n_edges, n_mol, M, sh);
}